// Round 13
// baseline (63.088 us; speedup 1.0000x reference)
//
#include <hip/hip_runtime.h>

#define NB 32
#define TT 512
#define SS 5
#define CC 512
#define UU 256
#define NEGV -1e30f
#define PKW 12                 // packed row width: e0..e3, b0..b4, pad x3
#define TREEB (2 * NB)         // 64 tree blocks: one per (n, sem)

// ---------------------------------------------------------------------------
// Kernel A: per-row sum-exp over C=512 (no-max LSE). At HBM roofline
// (27.6 us measured via round-10 marginal probe; 6.08 TB/s). Unchanged.
// ---------------------------------------------------------------------------
__global__ __launch_bounds__(512) void row_lse_kernel(
    const float* __restrict__ logits,   // [N][T][S][C]
    const int*   __restrict__ ranges,   // [N][T][S]
    const int*   __restrict__ y,        // [N][U]
    float*       __restrict__ packed,   // [T][N][PKW]
    int*         __restrict__ cnt)      // tree completion counter
{
    if (blockIdx.x == 0 && threadIdx.x == 0) *cnt = 0;

    const int lane = threadIdx.x & 63;
    const int row  = blockIdx.x * 8 + (threadIdx.x >> 6);  // 0..81919
    const float* rowp = logits + (size_t)row * CC;

    float4 a = *(const float4*)(rowp + lane * 4);          // floats [0,256)
    float4 b = *(const float4*)(rowp + 256 + lane * 4);    // floats [256,512)

    float s = __expf(a.x) + __expf(a.y) + __expf(a.z) + __expf(a.w)
            + __expf(b.x) + __expf(b.y) + __expf(b.z) + __expf(b.w);
#pragma unroll
    for (int off = 32; off; off >>= 1)
        s += __shfl_xor(s, off);

    const int   rg    = ranges[row];
    const int   n     = row / (TT * SS);
    const int   sy    = y[n * UU + rg];
    const float emraw = rowp[sy];
    const float blraw = rowp[0];
    const float lse   = __logf(s);

    if (lane == 0) {
        int loc  = row - n * (TT * SS);
        int t    = loc / SS;
        int sidx = loc - t * SS;
        float* dst = packed + ((size_t)t * NB + n) * PKW;
        if (sidx < 4) dst[sidx] = emraw - lse;   // em used only for s=0..3
        dst[4 + sidx] = blraw - lse;             // bl for s=0..4
    }
}

// ---------------------------------------------------------------------------
// Semiring helpers.
// ---------------------------------------------------------------------------
__device__ __forceinline__ float lse_corr(float x, float y) {
    return __logf(1.0f + __expf(-fabsf(x - y)));
}
template <bool MAXSEM>
__device__ __forceinline__ float combf(float x, float y) {
    return MAXSEM ? fmaxf(x, y) : fmaxf(x, y) + lse_corr(x, y);
}
template <bool MAXSEM>
__device__ __forceinline__ float fold5(float t0, float t1, float t2,
                                       float t3, float t4) {
    float c01 = combf<MAXSEM>(t0, t1);
    float c23 = combf<MAXSEM>(t2, t3);
    return combf<MAXSEM>(combf<MAXSEM>(c01, c23), t4);
}

// ---------------------------------------------------------------------------
// Kernel B: full scan in one kernel. One block per (n, sem), 64 blocks.
//  1) stage this n's packed rows; build all 512 per-timestep 5x5 matrices
//     ANALYTICALLY (prefix-sum differences; pure adds, no comb):
//       t < T-1: M[s][j] = pref[s+d]-pref[j] + b[s+d]   (s+d<=4, j<=s+d)
//       t = T-1: M[s][j] = pref[s]-pref[j]              (j<=s)
//     (matrix is semiring-independent; path weights only)
//  2) 9-level pairwise composition tree in LDS (ping-pong buffers):
//       (B*A)[s][j] = comb_q (B[s][q] + A[q][j])        (col-major j*5+s)
//  3) partials[bid] = -M_tot[4][0]; last-finishing block sums -> out[2].
// ---------------------------------------------------------------------------
template <bool MAXSEM>
__device__ __forceinline__ void tree_levels(
    float* __restrict__ bufA, float* __restrict__ bufB, int tid)
{
    float* src = bufA;
    float* dst = bufB;
    int m = TT;
    while (m > 1) {
        int pairs = m >> 1;
        for (int item = tid; item < pairs * 25; item += 320) {
            int p = item / 25, e = item - p * 25;
            int j = e / 5, s = e - j * 5;
            const float* A = src + (2 * p) * 25;       // earlier step
            const float* B = src + (2 * p + 1) * 25;   // later step
            float t0 = B[s]      + A[j * 5 + 0];
            float t1 = B[5 + s]  + A[j * 5 + 1];
            float t2 = B[10 + s] + A[j * 5 + 2];
            float t3 = B[15 + s] + A[j * 5 + 3];
            float t4 = B[20 + s] + A[j * 5 + 4];
            dst[item] = fold5<MAXSEM>(t0, t1, t2, t3, t4);
        }
        __syncthreads();
        float* tmp = src; src = dst; dst = tmp;
        m = pairs;
    }
    // result lives in src[0..24]; src == bufA after 9 levels (even swaps back)
}

__global__ __launch_bounds__(320) void scan_tree(
    const float* __restrict__ packed,   // [T][N][PKW]
    const int*   __restrict__ ranges,   // [N][T][S]
    float*       __restrict__ partials, // [TREEB]
    int*         __restrict__ cnt,
    float*       __restrict__ out)      // [2]
{
    __shared__ float bufA[TT * 25];            // 51.2 KB
    __shared__ float bufB[(TT / 2) * 25];      // 25.6 KB
    __shared__ float pref[TT][5];              // 10.2 KB  prefix sums of e
    __shared__ float bl[TT][5];                // 10.2 KB
    __shared__ unsigned char dsh[TT];          // 512 B    shift flags
    __shared__ int amLast;

    const int tid = threadIdx.x;               // 0..319
    const int bid = blockIdx.x;                // 0..63
    const int n   = bid & 31;
    const int sem = bid >> 5;                  // 0 = lse, 1 = max

    // ---- stage per-t data for this n ----
    for (int t = tid; t < TT; t += 320) {
        const float* src = packed + ((size_t)t * NB + n) * PKW;
        float e0 = src[0], e1 = src[1], e2 = src[2], e3 = src[3];
        pref[t][0] = 0.0f;
        pref[t][1] = e0;
        pref[t][2] = e0 + e1;
        pref[t][3] = e0 + e1 + e2;
        pref[t][4] = e0 + e1 + e2 + e3;
        bl[t][0] = src[4]; bl[t][1] = src[5]; bl[t][2] = src[6];
        bl[t][3] = src[7]; bl[t][4] = src[8];
    }
    for (int t = tid; t < TT; t += 320) {
        if (t < TT - 1) {
            int lb0 = ranges[(n * TT + t) * SS];
            int lb1 = ranges[(n * TT + t + 1) * SS];
            dsh[t] = (unsigned char)(lb1 != lb0);
        } else {
            dsh[t] = 0;
        }
    }
    __syncthreads();

    // ---- build per-t matrices analytically (pure adds, no comb) ----
    for (int item = tid; item < TT * 25; item += 320) {
        int t = item / 25, e = item - t * 25;
        int j = e / 5, s = e - j * 5;          // col-major: entry [s][j]
        float val;
        if (t < TT - 1) {
            int sp = s + (int)dsh[t];
            val = (sp <= 4 && j <= sp) ? (pref[t][sp] - pref[t][j] + bl[t][sp])
                                       : NEGV;
        } else {
            val = (j <= s) ? (pref[t][s] - pref[t][j]) : NEGV;
        }
        bufA[item] = val;
    }
    __syncthreads();

    // ---- composition tree ----
    if (sem == 0) tree_levels<false>(bufA, bufB, tid);
    else          tree_levels<true >(bufA, bufB, tid);

    // after 9 levels (odd count): result is in bufB? levels: 512->256(B),
    // 256->128(A), ->64(B), ->32(A), ->16(B), ->8(A), ->4(B), ->2(A), ->1(B).
    // 9 swaps: final result in bufB[0..24].
    if (tid == 0) partials[bid] = -bufB[4];    // -M_tot[4][0] (j=0,s=4)

    // ---- completion: last finishing block sums partials -> out ----
    __syncthreads();
    __threadfence();
    if (tid == 0) {
        int old = __hip_atomic_fetch_add(cnt, 1, __ATOMIC_ACQ_REL,
                                         __HIP_MEMORY_SCOPE_AGENT);
        amLast = (old == TREEB - 1);
    }
    __syncthreads();
    if (!amLast) return;
    __threadfence();                            // reader-side acquire

    if (tid < 64) {
        float v = partials[tid];                // lanes 0-31: lse, 32-63: max
#pragma unroll
        for (int off = 16; off; off >>= 1)
            v += __shfl_xor(v, off);
        if ((tid & 31) == 0)
            out[tid >> 5] = v;                  // out[0]=pruned, out[1]=one_best
    }
}

extern "C" void kernel_launch(void* const* d_in, const int* in_sizes, int n_in,
                              void* d_out, int out_size, void* d_ws, size_t ws_size,
                              hipStream_t stream) {
    const float* logits = (const float*)d_in[0];
    const int*   ranges = (const int*)d_in[1];
    const int*   y      = (const int*)d_in[2];
    // d_in[3] = x_lens, unused (reference ignores it; all == T)

    float* packed   = (float*)d_ws;                       // TT*NB*PKW floats
    float* partials = packed + (size_t)TT * NB * PKW;     // TREEB floats
    int*   cnt      = (int*)(partials + TREEB);           // 1 int
    float* out      = (float*)d_out;

    int rows = NB * TT * SS;                              // 81920
    hipLaunchKernelGGL(row_lse_kernel, dim3(rows / 8), dim3(512), 0, stream,
                       logits, ranges, y, packed, cnt);
    hipLaunchKernelGGL(scan_tree, dim3(TREEB), dim3(320), 0, stream,
                       packed, ranges, partials, cnt, out);
}

// Round 14
// 50.205 us; speedup vs baseline: 1.2566x; 1.2566x over previous
//
#include <hip/hip_runtime.h>

#define NB 32
#define TT 512
#define SS 5
#define CC 512
#define UU 256
#define NEGV -1e30f
#define LCH 8                  // timesteps per chunk
#define NCH (TT / LCH)         // 64 chunks
#define PKW 12                 // packed row width: e0..e3, b0..b4, pad x3
#define TREEB (2 * NB)         // 64 scan blocks: one per (n, sem)

// ---------------------------------------------------------------------------
// Kernel A: per-row sum-exp over C=512 (no-max LSE). At HBM roofline
// (27.6 us, round-10 marginal probe; 6.08 TB/s). Writes packed [n][t][PKW]
// so each scan block's slice is one contiguous 24 KB. Zeroes cnt.
// ---------------------------------------------------------------------------
__global__ __launch_bounds__(512) void row_lse_kernel(
    const float* __restrict__ logits,   // [N][T][S][C]
    const int*   __restrict__ ranges,   // [N][T][S]
    const int*   __restrict__ y,        // [N][U]
    float*       __restrict__ packed,   // [N][T][PKW]
    int*         __restrict__ cnt)      // completion counter
{
    if (blockIdx.x == 0 && threadIdx.x == 0) *cnt = 0;

    const int lane = threadIdx.x & 63;
    const int row  = blockIdx.x * 8 + (threadIdx.x >> 6);  // 0..81919
    const float* rowp = logits + (size_t)row * CC;

    float4 a = *(const float4*)(rowp + lane * 4);          // floats [0,256)
    float4 b = *(const float4*)(rowp + 256 + lane * 4);    // floats [256,512)

    float s = __expf(a.x) + __expf(a.y) + __expf(a.z) + __expf(a.w)
            + __expf(b.x) + __expf(b.y) + __expf(b.z) + __expf(b.w);
#pragma unroll
    for (int off = 32; off; off >>= 1)
        s += __shfl_xor(s, off);

    const int   rg    = ranges[row];
    const int   n     = row / (TT * SS);
    const int   sy    = y[n * UU + rg];
    const float emraw = rowp[sy];
    const float blraw = rowp[0];
    const float lse   = __logf(s);

    if (lane == 0) {
        int loc  = row - n * (TT * SS);
        int t    = loc / SS;
        int sidx = loc - t * SS;
        float* dst = packed + ((size_t)n * TT + t) * PKW;
        if (sidx < 4) dst[sidx] = emraw - lse;   // em used only for s=0..3
        dst[4 + sidx] = blraw - lse;             // bl for s=0..4
    }
}

// ---------------------------------------------------------------------------
// Semiring helpers.
// ---------------------------------------------------------------------------
__device__ __forceinline__ float lse_corr(float x, float y) {
    return __logf(1.0f + __expf(-fabsf(x - y)));
}
template <bool MAXSEM>
__device__ __forceinline__ float combf(float x, float y) {
    return MAXSEM ? fmaxf(x, y) : fmaxf(x, y) + lse_corr(x, y);
}
template <bool MAXSEM>
__device__ __forceinline__ float fold5(float t0, float t1, float t2,
                                       float t3, float t4) {
    float c01 = combf<MAXSEM>(t0, t1);
    float c23 = combf<MAXSEM>(t2, t3);
    return combf<MAXSEM>(combf<MAXSEM>(c01, c23), t4);
}

// ---------------------------------------------------------------------------
// Kernel B: whole scan, one block per (n, sem), no inter-block deps.
//  1) stage packed[n] (24 KB contiguous) + shift flags into LDS
//  2) 64 chunk-chains x 5 basis columns = 320 threads, depth-32 registers
//  3) 6-level pairwise composition tree in LDS (identical math to round 12)
//  4) partials[bid] = -M_tot[4][0]; last-finishing block sums -> out[2]
// ---------------------------------------------------------------------------
template <bool MAXSEM>
__device__ __forceinline__ void chain_and_tree(
    const float* __restrict__ pk, const unsigned char* __restrict__ dsh,
    float* __restrict__ matA, float* __restrict__ matB,
    float* __restrict__ partials, int bid, int tid)
{
    // ---- chunk chain: thread (c = tid&63, j = tid>>6) ----
    {
        const int j  = tid >> 6;          // basis column, wave-uniform
        const int c  = tid & 63;          // chunk
        const int t0 = c * LCH;

        float v0 = (j == 0) ? 0.0f : NEGV;
        float v1 = (j == 1) ? 0.0f : NEGV;
        float v2 = (j == 2) ? 0.0f : NEGV;
        float v3 = (j == 3) ? 0.0f : NEGV;
        float v4 = (j == 4) ? 0.0f : NEGV;

#pragma unroll
        for (int i = 0; i < LCH; ++i) {
            const float* row = pk + (t0 + i) * PKW;
            float e0 = row[0], e1 = row[1], e2 = row[2], e3 = row[3];

            v1 = combf<MAXSEM>(v1, v0 + e0);
            v2 = combf<MAXSEM>(v2, v1 + e1);
            v3 = combf<MAXSEM>(v3, v2 + e2);
            v4 = combf<MAXSEM>(v4, v3 + e3);

            if (t0 + i < TT - 1) {               // per-lane predicated
                float b0 = row[4], b1 = row[5], b2 = row[6];
                float b3 = row[7], b4 = row[8];
                bool sh = dsh[t0 + i] != 0;      // delta in {0,1}
                float n0 = sh ? v1 + b1 : v0 + b0;
                float n1 = sh ? v2 + b2 : v1 + b1;
                float n2 = sh ? v3 + b3 : v2 + b2;
                float n3 = sh ? v4 + b4 : v3 + b3;
                float n4 = sh ? NEGV    : v4 + b4;
                v0 = n0; v1 = n1; v2 = n2; v3 = n3; v4 = n4;
            }
        }
        float* outp = matA + c * 25 + j * 5;     // col-major m[j*5+s]
        outp[0] = v0; outp[1] = v1; outp[2] = v2; outp[3] = v3; outp[4] = v4;
    }
    __syncthreads();

    // ---- pairwise composition tree: 64 -> 1 ----
    float* src = matA;
    float* dst = matB;
    int m = NCH;
    while (m > 1) {
        int pairs = m >> 1;
        for (int item = tid; item < pairs * 25; item += 320) {
            int p = item / 25, e = item - p * 25;
            int j = e / 5, s = e - j * 5;
            const float* A = src + (2 * p) * 25;       // earlier chunk
            const float* B = src + (2 * p + 1) * 25;   // later chunk
            float t0 = B[s]      + A[j * 5 + 0];
            float t1 = B[5 + s]  + A[j * 5 + 1];
            float t2 = B[10 + s] + A[j * 5 + 2];
            float t3 = B[15 + s] + A[j * 5 + 3];
            float t4 = B[20 + s] + A[j * 5 + 4];
            dst[item] = fold5<MAXSEM>(t0, t1, t2, t3, t4);
        }
        __syncthreads();
        float* tmp = src; src = dst; dst = tmp;
        m = pairs;
    }
    // v_init = e0 -> answer = -M_tot[4][0] = -src[4]
    if (tid == 0) partials[bid] = -src[4];
}

__global__ __launch_bounds__(320) void scan_all(
    const float* __restrict__ packed,   // [N][T][PKW]
    const int*   __restrict__ ranges,   // [N][T][S]
    float*       __restrict__ partials, // [TREEB]
    int*         __restrict__ cnt,
    float*       __restrict__ out)      // [2]
{
    __shared__ float         pk[TT * PKW];      // 24 KB
    __shared__ unsigned char dsh[TT];           // 512 B
    __shared__ float         matA[NCH * 25];    // 6.4 KB
    __shared__ float         matB[(NCH / 2) * 25]; // 3.2 KB
    __shared__ int           amLast;

    const int tid = threadIdx.x;                // 0..319
    const int bid = blockIdx.x;                 // 0..63
    const int n   = bid & 31;
    const int sem = bid >> 5;                   // 0 = lse, 1 = max

    // ---- stage: contiguous 24 KB slice, coalesced float4 ----
    {
        const float4* gsrc = (const float4*)(packed + (size_t)n * TT * PKW);
        float4* ldst = (float4*)pk;
        for (int idx = tid; idx < TT * PKW / 4; idx += 320)
            ldst[idx] = gsrc[idx];
    }
    for (int t = tid; t < TT; t += 320) {
        dsh[t] = (t < TT - 1)
               ? (unsigned char)(ranges[(n * TT + t) * SS] !=
                                 ranges[(n * TT + t + 1) * SS])
               : (unsigned char)0;
    }
    __syncthreads();

    if (sem == 0) chain_and_tree<false>(pk, dsh, matA, matB, partials, bid, tid);
    else          chain_and_tree<true >(pk, dsh, matA, matB, partials, bid, tid);

    // ---- completion: last finishing block sums partials -> out ----
    __syncthreads();
    __threadfence();
    if (tid == 0) {
        int old = __hip_atomic_fetch_add(cnt, 1, __ATOMIC_ACQ_REL,
                                         __HIP_MEMORY_SCOPE_AGENT);
        amLast = (old == TREEB - 1);
    }
    __syncthreads();
    if (!amLast) return;
    __threadfence();                            // reader-side acquire

    if (tid < 64) {
        float v = partials[tid];                // lanes 0-31: lse, 32-63: max
#pragma unroll
        for (int off = 16; off; off >>= 1)
            v += __shfl_xor(v, off);
        if ((tid & 31) == 0)
            out[tid >> 5] = v;                  // out[0]=pruned, out[1]=one_best
    }
}

extern "C" void kernel_launch(void* const* d_in, const int* in_sizes, int n_in,
                              void* d_out, int out_size, void* d_ws, size_t ws_size,
                              hipStream_t stream) {
    const float* logits = (const float*)d_in[0];
    const int*   ranges = (const int*)d_in[1];
    const int*   y      = (const int*)d_in[2];
    // d_in[3] = x_lens, unused (reference ignores it; all == T)

    float* packed   = (float*)d_ws;                       // NB*TT*PKW floats
    float* partials = packed + (size_t)NB * TT * PKW;     // TREEB floats
    int*   cnt      = (int*)(partials + TREEB);           // 1 int
    float* out      = (float*)d_out;

    int rows = NB * TT * SS;                              // 81920
    hipLaunchKernelGGL(row_lse_kernel, dim3(rows / 8), dim3(512), 0, stream,
                       logits, ranges, y, packed, cnt);
    hipLaunchKernelGGL(scan_all, dim3(TREEB), dim3(320), 0, stream,
                       packed, ranges, partials, cnt, out);
}